// Round 1
// baseline (353.211 us; speedup 1.0000x reference)
//
#include <hip/hip_runtime.h>
#include <math.h>

typedef __bf16 bf16x8 __attribute__((ext_vector_type(8)));
typedef float f32x4 __attribute__((ext_vector_type(4)));
typedef unsigned short ushort8 __attribute__((ext_vector_type(8)));
typedef unsigned short u16;

#define DEVINL __device__ __forceinline__

// fp32 -> bf16 round-to-nearest-even (finite inputs only)
DEVINL u16 f2bf(float f) {
    union { float f; unsigned u; } a; a.f = f;
    unsigned u = a.u;
    return (u16)((u + 0x7FFFu + ((u >> 16) & 1u)) >> 16);
}
DEVINL float bf2f(u16 h) { return __uint_as_float(((unsigned)h) << 16); }

DEVINL void gload_lds16(const void* g, void* l) {
    __builtin_amdgcn_global_load_lds(
        (__attribute__((address_space(1))) void*)(g),
        (__attribute__((address_space(3))) void*)(l),
        16, 0, 0);
}

// ---------------------------------------------------------------------------
// m97-style 128x128 GEMM, C = A @ B^T (B stored [N,K] row-major), bf16 in.
// EPI 0: C(bf16) = acc + bias[col]
// EPI 1: C(bf16) = exp(acc * scale)
// EPI 2: C(f32)  = acc
// ---------------------------------------------------------------------------
template<int EPI>
__global__ __launch_bounds__(256, 2)
void gemm_bt(const u16* __restrict__ A, int lda, long sAz,
             const u16* __restrict__ B, int ldb, long sBz,
             void* __restrict__ Cv, int ldc, long sCz,
             const float* __restrict__ bias, float scale, int K)
{
    __shared__ u16 Alds[128 * 32];
    __shared__ u16 Blds[128 * 32];
    const int tid = threadIdx.x;
    const long bz = blockIdx.z;
    const u16* Ab = A + bz * sAz;
    const u16* Bb = B + bz * sBz;
    const int row0 = blockIdx.x * 128, col0 = blockIdx.y * 128;
    // staging: thread t loads rows (t/4 + i*64), cols (t%4)*8 .. +7  (16B)
    const int srow = tid >> 2, scol = (tid & 3) * 8;
    const u16* Ag = Ab + (long)(row0 + srow) * lda + scol;
    const u16* Bg = Bb + (long)(col0 + srow) * ldb + scol;
    const int lane = tid & 63, wave = tid >> 6;
    const int wr = (wave >> 1) * 64, wc = (wave & 1) * 64;  // wave tile origin
    const int fr = lane & 15, fk = (lane >> 4) * 8;
    f32x4 acc[4][4] = {};
    for (int kt = 0; kt < K; kt += 32) {
        __syncthreads();
        gload_lds16(Ag + kt,                   &Alds[tid * 8]);
        gload_lds16(Ag + kt + (long)64 * lda,  &Alds[2048 + tid * 8]);
        gload_lds16(Bg + kt,                   &Blds[tid * 8]);
        gload_lds16(Bg + kt + (long)64 * ldb,  &Blds[2048 + tid * 8]);
        __syncthreads();
        bf16x8 af[4], bfr[4];
#pragma unroll
        for (int m = 0; m < 4; ++m)
            af[m] = *(const bf16x8*)&Alds[(wr + m * 16 + fr) * 32 + fk];
#pragma unroll
        for (int n = 0; n < 4; ++n)
            bfr[n] = *(const bf16x8*)&Blds[(wc + n * 16 + fr) * 32 + fk];
#pragma unroll
        for (int m = 0; m < 4; ++m)
#pragma unroll
            for (int n = 0; n < 4; ++n)
                acc[m][n] = __builtin_amdgcn_mfma_f32_16x16x32_bf16(
                    af[m], bfr[n], acc[m][n], 0, 0, 0);
    }
    // epilogue: C/D layout col = lane&15, row = (lane>>4)*4 + reg
    const int crow = (lane >> 4) * 4, ccol = lane & 15;
#pragma unroll
    for (int m = 0; m < 4; ++m)
#pragma unroll
        for (int n = 0; n < 4; ++n) {
            const int gc = col0 + wc + n * 16 + ccol;
#pragma unroll
            for (int r = 0; r < 4; ++r) {
                const int gr = row0 + wr + m * 16 + crow + r;
                const float v = acc[m][n][r];
                if constexpr (EPI == 0) {
                    ((u16*)Cv)[bz * sCz + (long)gr * ldc + gc] = f2bf(v + bias[gc]);
                } else if constexpr (EPI == 1) {
                    ((u16*)Cv)[bz * sCz + (long)gr * ldc + gc] = f2bf(__expf(v * scale));
                } else {
                    ((float*)Cv)[bz * sCz + (long)gr * ldc + gc] = v;
                }
            }
        }
}

// ---------------------------------------------------------------------------
// x (fp32, 16384x1024) -> bf16, 8 elems/thread, 16B stores
// ---------------------------------------------------------------------------
__global__ void cast_x_k(const float* __restrict__ x, u16* __restrict__ o)
{
    const int i = blockIdx.x * 256 + threadIdx.x;   // 0 .. 2097151
    const float4* xv = (const float4*)x;
    const float4 a = xv[(long)i * 2], b = xv[(long)i * 2 + 1];
    ushort8 r;
    r[0] = f2bf(a.x); r[1] = f2bf(a.y); r[2] = f2bf(a.z); r[3] = f2bf(a.w);
    r[4] = f2bf(b.x); r[5] = f2bf(b.y); r[6] = f2bf(b.z); r[7] = f2bf(b.w);
    *(ushort8*)(o + (long)i * 8) = r;
}

// ---------------------------------------------------------------------------
// W[1024(in)][1024(out)] fp32 x3 -> Wt[3072(out)][1024(in)] bf16 (transpose)
// grid (32,32,3), block (32,8)
// ---------------------------------------------------------------------------
__global__ void wt_k(const float* __restrict__ Wq, const float* __restrict__ Wk,
                     const float* __restrict__ Wv, u16* __restrict__ Wt)
{
    __shared__ float t[32][33];
    const int z = blockIdx.z;
    const float* W = (z == 0) ? Wq : ((z == 1) ? Wk : Wv);
    const int k0 = blockIdx.x * 32, n0 = blockIdx.y * 32;
    const int tx = threadIdx.x, ty = threadIdx.y;
#pragma unroll
    for (int j = 0; j < 32; j += 8)
        t[ty + j][tx] = W[(long)(k0 + ty + j) * 1024 + n0 + tx];
    __syncthreads();
#pragma unroll
    for (int j = 0; j < 32; j += 8)
        Wt[((long)z * 1024 + n0 + ty + j) * 1024 + k0 + tx] = f2bf(t[tx][ty + j]);
}

__global__ void bias_k(const float* __restrict__ bq, const float* __restrict__ bk,
                       const float* __restrict__ bv, float* __restrict__ bcat)
{
    const int i = blockIdx.x * 256 + threadIdx.x;  // 0..3071
    bcat[i] = (i < 1024) ? bq[i] : ((i < 2048) ? bk[i - 1024] : bv[i - 2048]);
}

// ---------------------------------------------------------------------------
// column partial sums of E over q: part[b][qc][k] = sum_{q in qc*64..+63} E[b][q][k]
// grid (1, 32, 8), block 256, each thread handles 8 consecutive k
// ---------------------------------------------------------------------------
__global__ void colsum_k(const u16* __restrict__ E, float* __restrict__ part)
{
    const int b = blockIdx.z, qc = blockIdx.y;
    const int k8 = threadIdx.x;
    const u16* p = E + ((long)b * 2048 + qc * 64) * 2048 + k8 * 8;
    float s[8] = {};
#pragma unroll 4
    for (int q = 0; q < 64; ++q) {
        ushort8 v = *(const ushort8*)(p + (long)q * 2048);
#pragma unroll
        for (int j = 0; j < 8; ++j) s[j] += bf2f(v[j]);
    }
    float* o = part + ((long)b * 32 + qc) * 2048 + k8 * 8;
#pragma unroll
    for (int j = 0; j < 8; ++j) o[j] = s[j];
}

// rden[b][k] = 1 / sum_qc part[b][qc][k];  grid (8,8), block 256
__global__ void rcp_k(const float* __restrict__ part, float* __restrict__ rden)
{
    const int b = blockIdx.y;
    const int k = blockIdx.x * 256 + threadIdx.x;
    float s = 0.f;
#pragma unroll
    for (int qc = 0; qc < 32; ++qc) s += part[((long)b * 32 + qc) * 2048 + k];
    rden[b * 2048 + k] = 1.0f / s;
}

// ---------------------------------------------------------------------------
// Vt[b][d][k] = v[b][k][d] * rden[b][k]   (v = qkv[.., 2048+d], row stride 3072)
// grid (64, 32, 8), block (32,8)
// ---------------------------------------------------------------------------
__global__ void vt_k(const u16* __restrict__ qkv, const float* __restrict__ rden,
                     u16* __restrict__ Vt)
{
    __shared__ float t[32][33];
    const int b = blockIdx.z;
    const int k0 = blockIdx.x * 32, d0 = blockIdx.y * 32;
    const int tx = threadIdx.x, ty = threadIdx.y;
#pragma unroll
    for (int j = 0; j < 32; j += 8) {
        const int k = k0 + ty + j;
        t[ty + j][tx] = bf2f(qkv[((long)b * 2048 + k) * 3072 + 2048 + d0 + tx])
                        * rden[b * 2048 + k];
    }
    __syncthreads();
#pragma unroll
    for (int j = 0; j < 32; j += 8)
        Vt[((long)b * 1024 + d0 + ty + j) * 2048 + k0 + tx] = f2bf(t[tx][ty + j]);
}

// ---------------------------------------------------------------------------
extern "C" void kernel_launch(void* const* d_in, const int* in_sizes, int n_in,
                              void* d_out, int out_size, void* d_ws, size_t ws_size,
                              hipStream_t stream)
{
    const float* x  = (const float*)d_in[0];
    const float* Wq = (const float*)d_in[1];
    const float* bq = (const float*)d_in[2];
    const float* Wk = (const float*)d_in[3];
    const float* bk = (const float*)d_in[4];
    const float* Wv = (const float*)d_in[5];
    const float* bv = (const float*)d_in[6];

    char* ws = (char*)d_ws;
    u16*   qkv  = (u16*)(ws);                     // [16384][3072] bf16  = 100,663,296 B
    u16*   E    = (u16*)(ws + 100663296);         // [8][2048][2048] bf16 = 67,108,864 B
    u16*   Vt   = (u16*)(ws + 167772160);         // [8][1024][2048] bf16 = 33,554,432 B
    u16*   xb   = (u16*)(ws + 201326592);         // [16384][1024] bf16  = 33,554,432 B
    u16*   Wt   = (u16*)(ws + 234881024);         // [3072][1024] bf16   =  6,291,456 B
    float* bcat = (float*)(ws + 241172480);       // [3072] f32
    float* part = (float*)(ws + 241184768);       // [8][32][2048] f32   =  2,097,152 B
    float* rden = (float*)(ws + 243281920);       // [8][2048] f32

    const long sQKV = (long)2048 * 3072;
    const long sE   = (long)2048 * 2048;
    const long sVt  = (long)1024 * 2048;
    const long sO   = (long)2048 * 1024;

    // 1) casts
    cast_x_k<<<8192, 256, 0, stream>>>(x, xb);
    wt_k<<<dim3(32, 32, 3), dim3(32, 8), 0, stream>>>(Wq, Wk, Wv, Wt);
    bias_k<<<12, 256, 0, stream>>>(bq, bk, bv, bcat);
    // 2) qkv = x @ Wt^T + bias   (M=16384, N=3072, K=1024)
    gemm_bt<0><<<dim3(128, 24, 1), 256, 0, stream>>>(
        xb, 1024, 0, Wt, 1024, 0, qkv, 3072, 0, bcat, 0.f, 1024);
    // 3) E = exp(scale * Q @ K^T) per batch  (M=2048, N=2048, K=1024)
    gemm_bt<1><<<dim3(16, 16, 8), 256, 0, stream>>>(
        qkv, 3072, sQKV, qkv + 1024, 3072, sQKV, E, 2048, sE,
        nullptr, 0.03125f, 1024);
    // 4) column sums -> 1/denom; Vt = (v/denom)^T
    colsum_k<<<dim3(1, 32, 8), 256, 0, stream>>>(E, part);
    rcp_k<<<dim3(8, 8), 256, 0, stream>>>(part, rden);
    vt_k<<<dim3(64, 32, 8), dim3(32, 8), 0, stream>>>(qkv, rden, Vt);
    // 5) out = E @ Vt^T  (M=2048, N=1024, K=2048, fp32 out) per batch
    gemm_bt<2><<<dim3(16, 8, 8), 256, 0, stream>>>(
        E, 2048, sE, Vt, 2048, sVt, d_out, 1024, sO,
        nullptr, 1.f, 2048);
}

// Round 2
// 299.184 us; speedup vs baseline: 1.1806x; 1.1806x over previous
//
#include <hip/hip_runtime.h>
#include <math.h>

typedef __bf16 bf16x8 __attribute__((ext_vector_type(8)));
typedef float f32x4 __attribute__((ext_vector_type(4)));
typedef unsigned short ushort8 __attribute__((ext_vector_type(8)));
typedef unsigned short u16;

#define DEVINL __device__ __forceinline__

DEVINL u16 f2bf(float f) {
    union { float f; unsigned u; } a; a.f = f;
    unsigned u = a.u;
    return (u16)((u + 0x7FFFu + ((u >> 16) & 1u)) >> 16);
}
DEVINL float bf2f(u16 h) { return __uint_as_float(((unsigned)h) << 16); }

DEVINL void gload_lds16(const void* g, void* l) {
    __builtin_amdgcn_global_load_lds(
        (__attribute__((address_space(1))) void*)(g),
        (__attribute__((address_space(3))) void*)(l),
        16, 0, 0);
}

// ---------------------------------------------------------------------------
// 256x256 8-phase GEMM, C = A @ B^T (B stored [N,K] row-major), bf16 in.
// BK=64, 8 waves (2M x 4N), per-wave output 128x64, acc[8][4] f32x4.
// LDS: per matrix 2 dbuf x 2 K-slabs x (256 rows x 32 cols) bf16 = 64 KiB; 128 total.
// Schedule per K-tile: 4 phases, each {ds_read frags | issue 1 slab | bar |
// setprio(1) 16 MFMA setprio(0) | bar}; counted vmcnt(4) at phases 2,4.
// Slab issue stream: [A_s0, B_s0, A_s1, B_s1] of tile t+1 at phases 1..4 of t.
// LDS swizzle: byte-col ^= ((row>>1)&3)<<4  (applied on global SOURCE for the
// linear DMA dest, and on the ds_read address).
// EPI 0: C(bf16) = acc + bias[col];  EPI 1: C(bf16) = exp(acc*scale);  EPI 2: C(f32)=acc
// ---------------------------------------------------------------------------
template<int EPI>
__global__ __launch_bounds__(512, 2)
void gemm256(const u16* __restrict__ A, int lda, long sAz,
             const u16* __restrict__ B, int ldb, long sBz,
             void* __restrict__ Cv, int ldc, long sCz,
             const float* __restrict__ bias, float scale, int K)
{
    __shared__ u16 lds[65536];   // 128 KiB
    const int tid = threadIdx.x;
    const long bz = blockIdx.z;
    const u16* Ab = A + bz * sAz;
    const u16* Bb = B + bz * sBz;
    const int row0 = blockIdx.x * 256, col0 = blockIdx.y * 256;

    // staging: thread t covers LDS bytes [t*16, t*16+16) and +8192 of a slab.
    // slab layout [256 rows][32 cols] bf16 (64 B rows). row = tid>>2 (+128),
    // byte col = (tid&3)*16, pre-swizzled on the source side.
    const int sr = tid >> 2;
    const int csw = ((tid & 3) * 16) ^ (((sr >> 1) & 3) << 4);
    const u16* Ag = Ab + (long)(row0 + sr) * lda + (csw >> 1);
    const u16* Bg = Bb + (long)(col0 + sr) * ldb + (csw >> 1);
    const int dst0 = tid * 8;   // u16 index within slab

    // fragment reads: lane l reads row (+l&15), 16B slot (l>>4), swizzled.
    const int lane = tid & 63, wid = tid >> 6;
    const int wm = wid >> 2, wn = wid & 3;
    const int lane_r = lane & 15;
    const int rdcol = (((lane >> 4) * 16) ^ (((lane_r >> 1) & 3) << 4)) >> 1;
    const int arow0 = wm * 128 + lane_r;
    const int brow0 = wn * 64 + lane_r;

    const int NT = K >> 6;
    f32x4 acc[8][4] = {};
    bf16x8 af[4], bfrag[4];

    auto issueA = [&](int t1, int s, int buf) {
        const u16* g = Ag + (long)t1 * 64 + s * 32;
        u16* d = &lds[(buf * 2 + s) * 8192 + dst0];
        gload_lds16(g, d);
        gload_lds16(g + (long)128 * lda, d + 4096);
    };
    auto issueB = [&](int t1, int s, int buf) {
        const u16* g = Bg + (long)t1 * 64 + s * 32;
        u16* d = &lds[32768 + (buf * 2 + s) * 8192 + dst0];
        gload_lds16(g, d);
        gload_lds16(g + (long)128 * ldb, d + 4096);
    };

#define READ_A(s, h)                                                        \
    _Pragma("unroll")                                                       \
    for (int m = 0; m < 4; ++m)                                             \
        af[m] = *(const bf16x8*)&lds[(buf * 2 + (s)) * 8192 +               \
                     (arow0 + (h) * 64 + m * 16) * 32 + rdcol];

#define READ_B(s)                                                           \
    _Pragma("unroll")                                                       \
    for (int n = 0; n < 4; ++n)                                             \
        bfrag[n] = *(const bf16x8*)&lds[32768 + (buf * 2 + (s)) * 8192 +    \
                     (brow0 + n * 16) * 32 + rdcol];

#define MFMA16(h)                                                           \
    __builtin_amdgcn_s_setprio(1);                                          \
    _Pragma("unroll")                                                       \
    for (int m = 0; m < 4; ++m)                                             \
        _Pragma("unroll")                                                   \
        for (int n = 0; n < 4; ++n)                                         \
            acc[(h) * 4 + m][n] = __builtin_amdgcn_mfma_f32_16x16x32_bf16(  \
                af[m], bfrag[n], acc[(h) * 4 + m][n], 0, 0, 0);             \
    __builtin_amdgcn_s_setprio(0);

    // prologue: tile 0 -> buf 0; wait first two slabs (A_s0,B_s0), keep 2 in flight
    issueA(0, 0, 0); issueB(0, 0, 0); issueA(0, 1, 0); issueB(0, 1, 0);
    asm volatile("s_waitcnt vmcnt(4)" ::: "memory");
    __builtin_amdgcn_s_barrier();

    for (int t = 0; t < NT - 1; ++t) {
        const int buf = t & 1, nbuf = buf ^ 1;
        // phase 1 (s0,h0)
        READ_A(0, 0); READ_B(0);
        issueA(t + 1, 0, nbuf);
        __builtin_amdgcn_s_barrier();
        MFMA16(0);
        __builtin_amdgcn_s_barrier();
        // phase 2 (s0,h1)
        READ_A(0, 1);
        issueB(t + 1, 0, nbuf);
        asm volatile("s_waitcnt vmcnt(4)" ::: "memory");  // (t,A_s1),(t,B_s1) landed
        __builtin_amdgcn_s_barrier();
        MFMA16(1);
        __builtin_amdgcn_s_barrier();
        // phase 3 (s1,h0)
        READ_A(1, 0); READ_B(1);
        issueA(t + 1, 1, nbuf);
        __builtin_amdgcn_s_barrier();
        MFMA16(0);
        __builtin_amdgcn_s_barrier();
        // phase 4 (s1,h1)
        READ_A(1, 1);
        issueB(t + 1, 1, nbuf);
        asm volatile("s_waitcnt vmcnt(4)" ::: "memory");  // (t+1,A_s0),(t+1,B_s0) landed
        __builtin_amdgcn_s_barrier();
        MFMA16(1);
        __builtin_amdgcn_s_barrier();
    }
    {   // peeled last tile: no prefetch; one counted drain for its s1 slabs
        const int buf = (NT - 1) & 1;
        READ_A(0, 0); READ_B(0);
        __builtin_amdgcn_s_barrier();
        MFMA16(0);
        __builtin_amdgcn_s_barrier();
        READ_A(0, 1);
        asm volatile("s_waitcnt vmcnt(0)" ::: "memory");
        __builtin_amdgcn_s_barrier();
        MFMA16(1);
        __builtin_amdgcn_s_barrier();
        READ_A(1, 0); READ_B(1);
        __builtin_amdgcn_s_barrier();
        MFMA16(0);
        __builtin_amdgcn_s_barrier();
        READ_A(1, 1);
        __builtin_amdgcn_s_barrier();
        MFMA16(1);
    }
#undef READ_A
#undef READ_B
#undef MFMA16

    // epilogue: C/D layout col = lane&15, row = (lane>>4)*4 + reg
    const int crow = (lane >> 4) * 4, ccol = lane & 15;
#pragma unroll
    for (int mf = 0; mf < 8; ++mf)
#pragma unroll
        for (int nf = 0; nf < 4; ++nf) {
            const int gc = col0 + wn * 64 + nf * 16 + ccol;
#pragma unroll
            for (int r = 0; r < 4; ++r) {
                const int gr = row0 + wm * 128 + mf * 16 + crow + r;
                const float v = acc[mf][nf][r];
                if constexpr (EPI == 0) {
                    ((u16*)Cv)[bz * sCz + (long)gr * ldc + gc] = f2bf(v + bias[gc]);
                } else if constexpr (EPI == 1) {
                    ((u16*)Cv)[bz * sCz + (long)gr * ldc + gc] = f2bf(__expf(v * scale));
                } else {
                    ((float*)Cv)[bz * sCz + (long)gr * ldc + gc] = v;
                }
            }
        }
}

// ---------------------------------------------------------------------------
// x (fp32, 16384x1024) -> bf16
// ---------------------------------------------------------------------------
__global__ void cast_x_k(const float* __restrict__ x, u16* __restrict__ o)
{
    const int i = blockIdx.x * 256 + threadIdx.x;
    const float4* xv = (const float4*)x;
    const float4 a = xv[(long)i * 2], b = xv[(long)i * 2 + 1];
    ushort8 r;
    r[0] = f2bf(a.x); r[1] = f2bf(a.y); r[2] = f2bf(a.z); r[3] = f2bf(a.w);
    r[4] = f2bf(b.x); r[5] = f2bf(b.y); r[6] = f2bf(b.z); r[7] = f2bf(b.w);
    *(ushort8*)(o + (long)i * 8) = r;
}

// W[1024][1024] fp32 x3 -> Wt[3072][1024] bf16 (transpose); grid (32,32,3), block (32,8)
__global__ void wt_k(const float* __restrict__ Wq, const float* __restrict__ Wk,
                     const float* __restrict__ Wv, u16* __restrict__ Wt)
{
    __shared__ float t[32][33];
    const int z = blockIdx.z;
    const float* W = (z == 0) ? Wq : ((z == 1) ? Wk : Wv);
    const int k0 = blockIdx.x * 32, n0 = blockIdx.y * 32;
    const int tx = threadIdx.x, ty = threadIdx.y;
#pragma unroll
    for (int j = 0; j < 32; j += 8)
        t[ty + j][tx] = W[(long)(k0 + ty + j) * 1024 + n0 + tx];
    __syncthreads();
#pragma unroll
    for (int j = 0; j < 32; j += 8)
        Wt[((long)z * 1024 + n0 + ty + j) * 1024 + k0 + tx] = f2bf(t[tx][ty + j]);
}

__global__ void bias_k(const float* __restrict__ bq, const float* __restrict__ bk,
                       const float* __restrict__ bv, float* __restrict__ bcat)
{
    const int i = blockIdx.x * 256 + threadIdx.x;
    bcat[i] = (i < 1024) ? bq[i] : ((i < 2048) ? bk[i - 1024] : bv[i - 2048]);
}

// column partial sums of E over q; grid (1,32,8), block 256
__global__ void colsum_k(const u16* __restrict__ E, float* __restrict__ part)
{
    const int b = blockIdx.z, qc = blockIdx.y;
    const int k8 = threadIdx.x;
    const u16* p = E + ((long)b * 2048 + qc * 64) * 2048 + k8 * 8;
    float s[8] = {};
#pragma unroll 4
    for (int q = 0; q < 64; ++q) {
        ushort8 v = *(const ushort8*)(p + (long)q * 2048);
#pragma unroll
        for (int j = 0; j < 8; ++j) s[j] += bf2f(v[j]);
    }
    float* o = part + ((long)b * 32 + qc) * 2048 + k8 * 8;
#pragma unroll
    for (int j = 0; j < 8; ++j) o[j] = s[j];
}

// rden[b][k] = 1 / sum_qc part[b][qc][k];  grid (8,8), block 256
__global__ void rcp_k(const float* __restrict__ part, float* __restrict__ rden)
{
    const int b = blockIdx.y;
    const int k = blockIdx.x * 256 + threadIdx.x;
    float s = 0.f;
#pragma unroll
    for (int qc = 0; qc < 32; ++qc) s += part[((long)b * 32 + qc) * 2048 + k];
    rden[b * 2048 + k] = 1.0f / s;
}

// Vt[b][d][k] = v[b][k][d] * rden[b][k]; grid (64,32,8), block (32,8)
__global__ void vt_k(const u16* __restrict__ qkv, const float* __restrict__ rden,
                     u16* __restrict__ Vt)
{
    __shared__ float t[32][33];
    const int b = blockIdx.z;
    const int k0 = blockIdx.x * 32, d0 = blockIdx.y * 32;
    const int tx = threadIdx.x, ty = threadIdx.y;
#pragma unroll
    for (int j = 0; j < 32; j += 8) {
        const int k = k0 + ty + j;
        t[ty + j][tx] = bf2f(qkv[((long)b * 2048 + k) * 3072 + 2048 + d0 + tx])
                        * rden[b * 2048 + k];
    }
    __syncthreads();
#pragma unroll
    for (int j = 0; j < 32; j += 8)
        Vt[((long)b * 1024 + d0 + ty + j) * 2048 + k0 + tx] = f2bf(t[tx][ty + j]);
}

// ---------------------------------------------------------------------------
extern "C" void kernel_launch(void* const* d_in, const int* in_sizes, int n_in,
                              void* d_out, int out_size, void* d_ws, size_t ws_size,
                              hipStream_t stream)
{
    const float* x  = (const float*)d_in[0];
    const float* Wq = (const float*)d_in[1];
    const float* bq = (const float*)d_in[2];
    const float* Wk = (const float*)d_in[3];
    const float* bk = (const float*)d_in[4];
    const float* Wv = (const float*)d_in[5];
    const float* bv = (const float*)d_in[6];

    char* ws = (char*)d_ws;
    u16*   qkv  = (u16*)(ws);                     // [16384][3072] bf16
    u16*   E    = (u16*)(ws + 100663296);         // [8][2048][2048] bf16
    u16*   Vt   = (u16*)(ws + 167772160);         // [8][1024][2048] bf16
    u16*   xb   = (u16*)(ws + 201326592);         // [16384][1024] bf16
    u16*   Wt   = (u16*)(ws + 234881024);         // [3072][1024] bf16
    float* bcat = (float*)(ws + 241172480);       // [3072] f32
    float* part = (float*)(ws + 241184768);       // [8][32][2048] f32
    float* rden = (float*)(ws + 243281920);       // [8][2048] f32

    const long sQKV = (long)2048 * 3072;
    const long sE   = (long)2048 * 2048;
    const long sVt  = (long)1024 * 2048;
    const long sO   = (long)2048 * 1024;

    cast_x_k<<<8192, 256, 0, stream>>>(x, xb);
    wt_k<<<dim3(32, 32, 3), dim3(32, 8), 0, stream>>>(Wq, Wk, Wv, Wt);
    bias_k<<<12, 256, 0, stream>>>(bq, bk, bv, bcat);
    // qkv = x @ Wt^T + bias   (M=16384, N=3072, K=1024)
    gemm256<0><<<dim3(64, 12, 1), 512, 0, stream>>>(
        xb, 1024, 0, Wt, 1024, 0, qkv, 3072, 0, bcat, 0.f, 1024);
    // E = exp(scale * Q @ K^T) per batch  (M=N=2048, K=1024)
    gemm256<1><<<dim3(8, 8, 8), 512, 0, stream>>>(
        qkv, 3072, sQKV, qkv + 1024, 3072, sQKV, E, 2048, sE,
        nullptr, 0.03125f, 1024);
    colsum_k<<<dim3(1, 32, 8), 256, 0, stream>>>(E, part);
    rcp_k<<<dim3(8, 8), 256, 0, stream>>>(part, rden);
    vt_k<<<dim3(64, 32, 8), dim3(32, 8), 0, stream>>>(qkv, rden, Vt);
    // out = E @ Vt^T  (M=2048, N=1024, K=2048, fp32 out) per batch
    gemm256<2><<<dim3(8, 4, 8), 512, 0, stream>>>(
        E, 2048, sE, Vt, 2048, sVt, d_out, 1024, sO,
        nullptr, 1.f, 2048);
}